// Round 8
// baseline (136.955 us; speedup 1.0000x reference)
//
#include <hip/hip_runtime.h>
#include <hip/hip_bf16.h>

// B=4, C=256, N=HW=4096, Dqk=32.
// Round 16: byte-law confirmed 4x (cyc/body = bytes/~57 B/cyc/CU; R15 hit
// prediction exactly). Corollary: operand bytes = 32*gq + 8*gc KB scales with
// WAVE COUNT duplication -> 4 PV waves (gq=1,gc=4: each owns 64q x 64ch) give
// 64 KB vs 8 waves' 96. S side: 4 waves, one K-frag feeds FOUR q-tile MFMAs
// (K 8->4 KB). Total 112 -> 76 KB/body -> predicted attn ~36-42us.
// 512 thr = 4 PV + 4 S, 1 block/CU, __launch_bounds__(512,2) -> 256-VGPR cap,
// PV demand ~140 (NOT the R12 spill: there 64-cap vs 110 demand).
// Per-SIMD matrix work unchanged (576 cyc/body: 1 PV wave x 32 MFMA).
// Carried: wave-specialized attn, conflict-free 16B-slot P layout, K-dedup,
// x2 unroll named reg sets, SGPR-base addressing, &63 wrap prefetch,
// packed-Vp, S^T trick, LDS-only barrier, XCD swizzle, packed-W qkv,
// no-max softmax.

#define N_PIX 4096
#define DQK   32
#define CCH   256
#define LOG2E 1.44269504088896f

typedef __attribute__((ext_vector_type(8))) _Float16 f16x8;
typedef __attribute__((ext_vector_type(4))) _Float16 f16x4;
typedef __attribute__((ext_vector_type(2))) _Float16 f16x2;
typedef __attribute__((ext_vector_type(8))) short    bf16x8;
typedef __attribute__((ext_vector_type(4))) short    bf16x4;
typedef __attribute__((ext_vector_type(4))) float    f32x4;

// LDS-only block barrier: waits lgkmcnt(0) but leaves vmcnt untouched.
__device__ inline void barrier_lds() {
    asm volatile("" ::: "memory");
    __builtin_amdgcn_s_waitcnt(0xc07f);   // vmcnt=63, expcnt=7, lgkmcnt=0
    __builtin_amdgcn_s_barrier();
    asm volatile("" ::: "memory");
}

// pack two f32 -> two bf16 in one instruction (RNE)
__device__ inline unsigned cvt_pk_bf16(float lo, float hi) {
    unsigned r;
    asm("v_cvt_pk_bf16_f32 %0, %1, %2" : "=v"(r) : "v"(lo), "v"(hi));
    return r;
}

// ---------------------------------------------------------------------------
// Kernel 0: pack Wq|Wk|Wv -> f16 A-fragments, lane-ordered (LOG2E folded into Wq).
// ---------------------------------------------------------------------------
__global__ __launch_bounds__(256) void wpack_kernel(
    const float* __restrict__ Wq, const float* __restrict__ Wk,
    const float* __restrict__ Wv, _Float16* __restrict__ Wp)
{
    const int tid   = threadIdx.x;
    const int wflat = blockIdx.x * 4 + (tid >> 6);   // 0..159
    const int lane  = tid & 63;
    const int L15   = lane & 15;
    const int quad  = lane >> 4;
    const int mt    = wflat >> 3;
    const int ks    = wflat & 7;
    const int m0    = mt * 16;

    const float* Wsrc; int row; float scale = 1.f;
    if (m0 < 32)      { Wsrc = Wq; row = m0 + L15;      scale = LOG2E; }
    else if (m0 < 64) { Wsrc = Wk; row = m0 - 32 + L15; }
    else              { Wsrc = Wv; row = m0 - 64 + L15; }

    const float* p = Wsrc + (size_t)row * 256 + ks * 32 + quad * 8;
    f16x8 h;
    #pragma unroll
    for (int j = 0; j < 8; ++j) h[j] = (_Float16)(p[j] * scale);
    *(f16x8*)(Wp + ((size_t)wflat * 64 + lane) * 8) = h;
}

// ---------------------------------------------------------------------------
// Kernel 1: QKV projection, f16 MFMA, packed W. Grid 512, 640 thr = 10 waves,
// 32-pixel tiles. Wave wid owns m-tiles {2*wid, 2*wid+1}; A-frags held in
// registers per ks-step and reused across BOTH 16-pixel halves.
// V output goes through LDS transpose -> packed B-frag layout:
//   Vp[b][(n0>>5)*16 + cg16][lane(quad,L15)][j] = v[cg16*16+L15][n0 + quad*8+j]
// ---------------------------------------------------------------------------
__global__ __launch_bounds__(640, 5) void qkv_kernel(
    const float* __restrict__ x, const _Float16* __restrict__ Wp,
    const float* __restrict__ bq, const float* __restrict__ bk,
    const float* __restrict__ bv,
    _Float16* __restrict__ qo, _Float16* __restrict__ ko,
    __hip_bfloat16* __restrict__ vp)
{
    // shared: xT (32x264 f16 = 16.9KB) then reused as vst (256x40 bf16 = 20KB)
    __shared__ alignas(16) unsigned char shraw[256 * 40 * 2];
    _Float16       (*xT)[264] = (_Float16 (*)[264])shraw;
    __hip_bfloat16 (*vst)[40] = (__hip_bfloat16 (*)[40])shraw;

    const int idx = blockIdx.x;
    const int b   = (idx & 7) >> 1;
    const int n0  = (((idx >> 3) << 1) | (idx & 1)) * 32;
    const int tid = threadIdx.x;

    // stage x[256c][32n] -> xT[n][c] f16  (1024 slots over 640 threads)
    {
        const float* xb = x + (size_t)b * CCH * N_PIX;
        #pragma unroll
        for (int pass = 0; pass < 2; ++pass) {
            const int slot = pass * 640 + tid;
            if (slot < 1024) {
                const int c2 = (slot >> 3) * 2;
                const int n4 = (slot & 7) * 4;
                const float4 r0 = *(const float4*)(xb + (size_t)c2       * N_PIX + n0 + n4);
                const float4 r1 = *(const float4*)(xb + (size_t)(c2 + 1) * N_PIX + n0 + n4);
                const float a[4] = {r0.x, r0.y, r0.z, r0.w};
                const float c[4] = {r1.x, r1.y, r1.z, r1.w};
                #pragma unroll
                for (int i = 0; i < 4; ++i)
                    *(f16x2*)(&xT[n4 + i][c2]) = (f16x2){(_Float16)a[i], (_Float16)c[i]};
            }
        }
    }
    __syncthreads();

    const int lane = tid & 63;
    const int wid  = tid >> 6;   // 0..9, owns m-tiles {2wid, 2wid+1}
    const int L15  = lane & 15;
    const int quad = lane >> 4;

    const f32x4 fz = {0.f, 0.f, 0.f, 0.f};
    f32x4 acc[2][2];   // [j (m-tile)][nf (pixel half)]
    #pragma unroll
    for (int j = 0; j < 2; ++j) { acc[j][0] = fz; acc[j][1] = fz; }

    const _Float16* wpw = Wp + ((size_t)(wid * 2) * 8 * 64 + lane) * 8;

    #pragma unroll
    for (int ks = 0; ks < 8; ++ks) {
        const f16x8 a0 = *(const f16x8*)(wpw + (size_t)(0 * 8 + ks) * 512);
        const f16x8 a1 = *(const f16x8*)(wpw + (size_t)(1 * 8 + ks) * 512);
        #pragma unroll
        for (int nf = 0; nf < 2; ++nf) {
            const f16x8 bfr = *(const f16x8*)(&xT[nf * 16 + L15][ks * 32 + quad * 8]);
            acc[0][nf] = __builtin_amdgcn_mfma_f32_16x16x32_f16(a0, bfr, acc[0][nf], 0, 0, 0);
            acc[1][nf] = __builtin_amdgcn_mfma_f32_16x16x32_f16(a1, bfr, acc[1][nf], 0, 0, 0);
        }
    }

    // q/k epilogue (global, no LDS): C/D row = out-row (quad*4+r), col = pixel (L15)
    #pragma unroll
    for (int j = 0; j < 2; ++j) {
        const int m0 = (wid * 2 + j) * 16;
        if (m0 < 32) {
            const int mr = m0 + quad * 4;
            #pragma unroll
            for (int nf = 0; nf < 2; ++nf) {
                const int n = n0 + nf * 16 + L15;
                f16x4 h;
                #pragma unroll
                for (int r = 0; r < 4; ++r) h[r] = (_Float16)(acc[j][nf][r] + bq[mr + r] * LOG2E);
                *(f16x4*)(qo + ((size_t)b * N_PIX + n) * DQK + mr) = h;
            }
        } else if (m0 < 64) {
            const int mr = m0 - 32 + quad * 4;
            #pragma unroll
            for (int nf = 0; nf < 2; ++nf) {
                const int n = n0 + nf * 16 + L15;
                f16x4 h;
                #pragma unroll
                for (int r = 0; r < 4; ++r) h[r] = (_Float16)(acc[j][nf][r] + bk[mr + r]);
                *(f16x4*)(ko + ((size_t)b * N_PIX + n) * DQK + mr) = h;
            }
        }
    }

    __syncthreads();   // xT dead; vst aliases it

    // v -> LDS transpose buffer vst[ch][pix] (rows padded to 40 elems, 16B-aligned)
    #pragma unroll
    for (int j = 0; j < 2; ++j) {
        const int m0 = (wid * 2 + j) * 16;
        if (m0 >= 64) {
            const int c = m0 - 64 + quad * 4;
            #pragma unroll
            for (int nf = 0; nf < 2; ++nf) {
                const int np = nf * 16 + L15;
                #pragma unroll
                for (int r = 0; r < 4; ++r)
                    vst[c + r][np] = __float2bfloat16(acc[j][nf][r] + bv[c + r]);
            }
        }
    }
    __syncthreads();

    // packed store: slot (cg16, lane'=(qd,l15)) -> one b128 LDS read + one 16B store
    {
        __hip_bfloat16* vpb = vp + (size_t)b * 2048 * 512 + (size_t)((n0 >> 5) * 16) * 512;
        #pragma unroll
        for (int s = 0; s < 2; ++s) {
            const int slot = s * 640 + tid;   // 0..1279, use 0..1023
            if (slot < 1024) {
                const int cg16 = slot >> 6;
                const int ln   = slot & 63;
                const int qd   = ln >> 4;
                const int l15  = ln & 15;
                const bf16x8 val = *(const bf16x8*)(&vst[cg16 * 16 + l15][qd * 8]);
                *(bf16x8*)(vpb + ((size_t)cg16 * 64 + ln) * 8) = val;
            }
        }
    }
}

// ---------------------------------------------------------------------------
// Kernel 2: attention. Grid 256 (XCD-swizzled), 512 threads = 8 waves,
// 64 q/block, 1 block/CU, 2 waves/SIMD (256-VGPR cap). Wave-specialized:
//   PV waves (wid 0..3): cg owns 64 ch x all 64 q. Per body: 8 x 1KB Ps
//     reads + 32 MFMA + 8 V chunk loads. Duplication minimized: P tile read
//     4x (32KB), V tile once (32KB).
//   S waves (wid 4..7): skt = wid-4 owns k-tile skt for ALL FOUR q-tiles:
//     ONE 1KB K-frag feeds 4 MFMAs (aq0..aq3 in regs) -> K 4KB/body.
//     16 exp2 + 4 uint2 P writes per body.
// P layout: Ps[buf][g][kb8][L15][8e]; tile (qt,skt) -> g = 2*qt + (skt>>1),
// kb8 = (skt&1)*2+(quad>>1), elem (quad&1)*4. PV reads 1KB contiguous
// (0 conflicts), S uint2 writes 4/bank balanced.
// Per-body bytes: 32 P-read + 32 V + 4 K + 8 P-write = 76 KB (was 112).
// ---------------------------------------------------------------------------

#define PV_BODY(J, VR)                                                            \
  {                                                                               \
    const int buf_ = (J) & 1;                                                     \
    _Pragma("unroll")                                                             \
    for (int qq_ = 0; qq_ < 4; ++qq_) {                                           \
      _Pragma("unroll")                                                           \
      for (int kk_ = 0; kk_ < 2; ++kk_) {                                         \
        const bf16x8 ap_ = *(const bf16x8*)(&Ps[buf_][qq_ * 2 + kk_][quad][L15][0]); \
        _Pragma("unroll")                                                         \
        for (int cf_ = 0; cf_ < 4; ++cf_)                                         \
          oacc[qq_][cf_] = __builtin_amdgcn_mfma_f32_16x16x32_bf16(               \
              ap_, VR[kk_][cf_], oacc[qq_][cf_], 0, 0, 0);                        \
      }                                                                           \
    }                                                                             \
    const __hip_bfloat16* vt_ = vb + (size_t)(((J) + 2) & 63) * 16384;            \
    _Pragma("unroll")                                                             \
    for (int kk_ = 0; kk_ < 2; ++kk_)                                             \
      _Pragma("unroll")                                                           \
      for (int cf_ = 0; cf_ < 4; ++cf_)                                           \
        VR[kk_][cf_] = *(const bf16x8*)(vt_ + voff0 + kk_ * 8192 + cf_ * 512);    \
  }

// exp + pack + store one q-tile's S quad-column (16 values per lane-group)
#define S_QT(SACC, PSUM, QT, BUFW)                                                \
  {                                                                               \
    const float a0_ = exp2f(SACC[0]), a1_ = exp2f(SACC[1]);                       \
    const float a2_ = exp2f(SACC[2]), a3_ = exp2f(SACC[3]);                       \
    PSUM += (a0_ + a1_) + (a2_ + a3_);                                            \
    uint2 w_; w_.x = cvt_pk_bf16(a0_, a1_); w_.y = cvt_pk_bf16(a2_, a3_);         \
    *(uint2*)(&Ps[BUFW][(QT) * 2 + kh][s8][L15][e4]) = w_;                        \
  }

// S body J: computes S(J+1) for tiles (0..3, skt) from KR = K(J+1), writes
// P(J+1) to buf (J&1)^1, prefetches K(J+3) into KR.
#define S_BODY(J, KR, DO_S)                                                       \
  {                                                                               \
    if (DO_S) {                                                                   \
      const int bufw_ = ((J) & 1) ^ 1;                                            \
      const f32x4 s0_ = __builtin_amdgcn_mfma_f32_16x16x32_f16(KR, aq0, fz, 0, 0, 0); \
      const f32x4 s1_ = __builtin_amdgcn_mfma_f32_16x16x32_f16(KR, aq1, fz, 0, 0, 0); \
      const f32x4 s2_ = __builtin_amdgcn_mfma_f32_16x16x32_f16(KR, aq2, fz, 0, 0, 0); \
      const f32x4 s3_ = __builtin_amdgcn_mfma_f32_16x16x32_f16(KR, aq3, fz, 0, 0, 0); \
      const _Float16* kp_ = kbp + (size_t)(((J) + 3) & 63) * (64 * DQK);          \
      KR = *(const f16x8*)(kp_ + koff);                                           \
      S_QT(s0_, psum0, 0, bufw_)                                                  \
      S_QT(s1_, psum1, 1, bufw_)                                                  \
      S_QT(s2_, psum2, 2, bufw_)                                                  \
      S_QT(s3_, psum3, 3, bufw_)                                                  \
    }                                                                             \
  }

__global__ __launch_bounds__(512, 2) void attn_kernel(
    const _Float16* __restrict__ qg,        // [B][N][32], q pre-scaled by log2e
    const _Float16* __restrict__ kg,        // [B][N][32]
    const __hip_bfloat16* __restrict__ vp,  // packed: [B][2048 chunks][64][8]
    float* __restrict__ out)                // [B][C][N]
{
    __shared__ __hip_bfloat16 Ps[2][8][4][16][8];   // 16KB; [buf][g][kb8][L15][e]
    __shared__ float lsum[4][4][16];                // [qt][skt][query]

    const int idx  = blockIdx.x;
    const int b    = (idx & 7) >> 1;
    const int n0   = (((idx >> 3) << 1) | (idx & 1)) * 64;
    const int tid  = threadIdx.x;
    const int wid  = tid >> 6;   // 0..7
    const int lane = tid & 63;
    const int L15  = lane & 15;
    const int quad = lane >> 4;
    const bool is_pv = (wid < 4);

    const f32x4 fz = {0.f, 0.f, 0.f, 0.f};

    // ---- PV-wave state (wid 0..3): all 64 q x 64-channel group
    const int cg = wid & 3;                        // 64-channel group
    const __hip_bfloat16* vb = vp + (size_t)b * 2048 * 512;
    const int voff0 = lane * 8 + cg * 4 * 512;     // + kk*8192 + cf*512
    f32x4 oacc[4][4];                              // [q-tile][cf] = 64 VGPR
    #pragma unroll
    for (int qq = 0; qq < 4; ++qq)
        #pragma unroll
        for (int cf = 0; cf < 4; ++cf) oacc[qq][cf] = fz;
    bf16x8 vA[2][4], vB[2][4];                     // 64 VGPR

    // ---- S-wave state (wid 4..7): skt = wid-4; ALL 4 q-tiles per K-frag
    const int skt = wid & 3;
    const int kh  = skt >> 1;                      // group k-half
    const int s8  = (skt & 1) * 2 + (quad >> 1);   // kb8 slot within group
    const int e4  = (quad & 1) * 4;                // element offset
    const _Float16* kbp = kg + (size_t)b * N_PIX * DQK;
    const int koff = (skt * 16 + L15) * DQK + quad * 8;
    f16x8 aq0{}, aq1{}, aq2{}, aq3{}, kA{}, kB{};
    float psum0 = 0.f, psum1 = 0.f, psum2 = 0.f, psum3 = 0.f;

    // ---- prologue
    if (is_pv) {
        #pragma unroll
        for (int kk = 0; kk < 2; ++kk)
            #pragma unroll
            for (int cf = 0; cf < 4; ++cf) {
                vA[kk][cf] = *(const bf16x8*)(vb +         voff0 + kk * 8192 + cf * 512);
                vB[kk][cf] = *(const bf16x8*)(vb + 16384 + voff0 + kk * 8192 + cf * 512);
            }
    } else {
        const _Float16* qbase = qg + ((size_t)b * N_PIX + n0 + L15) * DQK + quad * 8;
        aq0 = *(const f16x8*)(qbase + (size_t)(0 * 16) * DQK);
        aq1 = *(const f16x8*)(qbase + (size_t)(1 * 16) * DQK);
        aq2 = *(const f16x8*)(qbase + (size_t)(2 * 16) * DQK);
        aq3 = *(const f16x8*)(qbase + (size_t)(3 * 16) * DQK);
        const f16x8 k00 = *(const f16x8*)(kbp + koff);
        kA = *(const f16x8*)(kbp + (size_t)1 * 64 * DQK + koff);
        kB = *(const f16x8*)(kbp + (size_t)2 * 64 * DQK + koff);
        const f32x4 s0 = __builtin_amdgcn_mfma_f32_16x16x32_f16(k00, aq0, fz, 0, 0, 0);
        const f32x4 s1 = __builtin_amdgcn_mfma_f32_16x16x32_f16(k00, aq1, fz, 0, 0, 0);
        const f32x4 s2 = __builtin_amdgcn_mfma_f32_16x16x32_f16(k00, aq2, fz, 0, 0, 0);
        const f32x4 s3 = __builtin_amdgcn_mfma_f32_16x16x32_f16(k00, aq3, fz, 0, 0, 0);
        S_QT(s0, psum0, 0, 0)
        S_QT(s1, psum1, 1, 0)
        S_QT(s2, psum2, 2, 0)
        S_QT(s3, psum3, 3, 0)
    }
    barrier_lds();

    // ---- main loop: 64 bodies, x2 unrolled (P(J) lives in buf J&1)
    for (int it = 0; it < 64; it += 2) {
        if (is_pv) { PV_BODY(it, vA) } else { S_BODY(it, kA, true) }
        barrier_lds();
        if (is_pv) { PV_BODY(it + 1, vB) } else { S_BODY(it + 1, kB, it < 62) }
        barrier_lds();
    }

    // ---- epilogue: S waves publish row-sums, PV waves normalize + store
    if (!is_pv) {
        psum0 += __shfl_xor(psum0, 16, 64);
        psum0 += __shfl_xor(psum0, 32, 64);
        psum1 += __shfl_xor(psum1, 16, 64);
        psum1 += __shfl_xor(psum1, 32, 64);
        psum2 += __shfl_xor(psum2, 16, 64);
        psum2 += __shfl_xor(psum2, 32, 64);
        psum3 += __shfl_xor(psum3, 16, 64);
        psum3 += __shfl_xor(psum3, 32, 64);
        if (quad == 0) {
            lsum[0][skt][L15] = psum0;
            lsum[1][skt][L15] = psum1;
            lsum[2][skt][L15] = psum2;
            lsum[3][skt][L15] = psum3;
        }
    }
    __syncthreads();

    if (is_pv) {
        float* ob = out + (size_t)b * CCH * N_PIX;
        #pragma unroll
        for (int qq = 0; qq < 4; ++qq) {
            float inv_l[4];
            #pragma unroll
            for (int r = 0; r < 4; ++r) {
                const int q = quad * 4 + r;
                inv_l[r] = 1.f / (lsum[qq][0][q] + lsum[qq][1][q] +
                                  lsum[qq][2][q] + lsum[qq][3][q]);
            }
            #pragma unroll
            for (int cf = 0; cf < 4; ++cf) {
                const int c = cg * 64 + cf * 16 + L15;
                f32x4 o;
                #pragma unroll
                for (int r = 0; r < 4; ++r) o[r] = oacc[qq][cf][r] * inv_l[r];
                *(f32x4*)(ob + (size_t)c * N_PIX + n0 + qq * 16 + quad * 4) = o;
            }
        }
    }
}

// ---------------------------------------------------------------------------
extern "C" void kernel_launch(void* const* d_in, const int* in_sizes, int n_in,
                              void* d_out, int out_size, void* d_ws, size_t ws_size,
                              hipStream_t stream) {
    (void)in_sizes; (void)n_in; (void)out_size; (void)ws_size;
    const float* x  = (const float*)d_in[0];
    const float* Wq = (const float*)d_in[1];
    const float* bq = (const float*)d_in[2];
    const float* Wk = (const float*)d_in[3];
    const float* bk = (const float*)d_in[4];
    const float* Wv = (const float*)d_in[5];
    const float* bv = (const float*)d_in[6];

    // workspace: q 1MB | k 1MB | Vp 8MB | Wp 160KB
    _Float16* qb = (_Float16*)d_ws;
    _Float16* kb = qb + (size_t)4 * N_PIX * DQK;
    __hip_bfloat16* vpk = (__hip_bfloat16*)(kb + (size_t)4 * N_PIX * DQK);
    _Float16* wp = (_Float16*)(vpk + (size_t)4 * 2048 * 512);
    float* outp = (float*)d_out;

    wpack_kernel<<<40, 256, 0, stream>>>(Wq, Wk, Wv, wp);
    qkv_kernel<<<512, 640, 0, stream>>>(x, wp, bq, bk, bv, qb, kb, vpk);
    attn_kernel<<<256, 512, 0, stream>>>(qb, kb, vpk, outp);
}